// Round 5
// baseline (24200.510 us; speedup 1.0000x reference)
//
#include <hip/hip_runtime.h>
#include <hip/hip_cooperative_groups.h>

namespace cg = cooperative_groups;

typedef unsigned short ushort_t;
typedef __attribute__((ext_vector_type(8))) short bf16x8;
typedef __attribute__((ext_vector_type(4))) float f32x4;

#define B_    1024
#define H_    1024
#define FEAT_ 75
#define KP_   1120          // packed K: 1024 h + 75 x + 21 zero pad
#define NK_   35            // K-steps of 32
#define OFF_CP 1920000UL    // 1024*25*75
#define OFF_CV 5760000UL    // OFF_CP + 1024*50*75

__device__ __forceinline__ float bf2f(ushort_t u) {
    unsigned x = ((unsigned)u) << 16;
    float f; __builtin_memcpy(&f, &x, 4); return f;
}
__device__ __forceinline__ ushort_t f2bf(float f) {
    unsigned x; __builtin_memcpy(&x, &f, 4);
    x += 0x7fffu + ((x >> 16) & 1u);          // RNE
    return (ushort_t)(x >> 16);
}
__device__ __forceinline__ float sigm(float x) { return 1.f / (1.f + __expf(-x)); }

__device__ __forceinline__ void gload16(const void* g, void* l) {
    __builtin_amdgcn_global_load_lds(
        (const __attribute__((address_space(1))) void*)g,
        (__attribute__((address_space(3))) void*)l, 16, 0, 0);
}

// ---------------------------------------------------------------------------
// One LSTM timestep for one (ct, rt) tile: 64 rows x 64 j x 4 gates, 4 waves.
// bf16 MFMA 16x16x32, D=2 LDS pipeline with counted vmcnt(5), raw barriers.
// Epilogue fuses the LSTM cell and writes h_t (bf16) into Aout.
// Proven correct in round 2/3 (absmax 0.031).
// ---------------------------------------------------------------------------
__device__ __forceinline__ void lstm_step_body(
    char* lds,
    const ushort_t* __restrict__ Ain, ushort_t* __restrict__ Aout,
    const ushort_t* __restrict__ Wt,  const float* __restrict__ bias,
    float* __restrict__ cst,
    const ushort_t* xnext, int xstride,
    int ct, int rt, int tid)
{
    const int w    = tid >> 6;       // wave 0..3
    const int l    = tid & 63;       // lane
    const int j0   = ct * 64;
    const int row0 = rt * 64;

    // ---- x_{t+1} copy into Aout (encoders only, ct==0 blocks) ----
    if (ct == 0 && xnext) {
        for (int idx = tid; idx < 64 * 96; idx += 256) {
            const int r  = idx / 96;
            const int xi = idx - r * 96;
            const int grow = row0 + r;
            ushort_t v = (xi < FEAT_) ? xnext[(size_t)grow * xstride + xi] : (ushort_t)0;
            Aout[(size_t)grow * KP_ + 1024 + xi] = v;
        }
    }
    // pin the vmem counter base so the counted vmcnt(5) below only ever
    // counts staging loads (x-copy / prior-phase stores fully retired here)
    asm volatile("s_waitcnt vmcnt(0)" ::: "memory");

    // ---- staging addresses (global_load_lds: per-lane src, uniform LDS base) ----
    const int lc4  = l & 3;
    const int lr4  = l >> 2;
    const int csrc = lc4 ^ (lr4 & 3);       // inverse-swizzled source chunk

    const ushort_t* agsrc = Ain + (size_t)(row0 + w * 16 + lr4) * KP_ + csrc * 8;
    char* aldst = lds + (w * 16) * 64;

    const ushort_t* bgsrc[4];
    char* bldst[4];
    #pragma unroll
    for (int i = 0; i < 4; ++i) {
        const int wcol = w * 1024 + j0 + i * 16 + lr4;   // gate panel w
        bgsrc[i] = Wt + (size_t)wcol * KP_ + csrc * 8;
        bldst[i] = lds + 4096 + (w * 64 + i * 16) * 64;
    }

    // ---- read offsets: LDS[r][c] holds global chunk c ^ (r&3) ----
    const int chsw = (((l >> 4) ^ (l & 3)) << 4);
    int aoff[4], boff[4];
    #pragma unroll
    for (int m = 0; m < 4; ++m) aoff[m] = (m * 16 + (l & 15)) * 64 + chsw;
    #pragma unroll
    for (int g = 0; g < 4; ++g) boff[g] = 4096 + (g * 64 + w * 16 + (l & 15)) * 64 + chsw;

    f32x4 acc[4][4];
    #pragma unroll
    for (int m = 0; m < 4; ++m)
        #pragma unroll
        for (int g = 0; g < 4; ++g)
            acc[m][g] = (f32x4){0.f, 0.f, 0.f, 0.f};

    // ---- prologue: stage K-step 0 into buf0 ----
    gload16(agsrc, aldst);
    #pragma unroll
    for (int i = 0; i < 4; ++i) gload16(bgsrc[i], bldst[i]);

    // ---- main loop: 2-phase, counted vmcnt, raw barriers ----
    int bi = 0;
    for (int kt = 0; kt < NK_; ++kt) {
        if (kt + 1 < NK_) {
            const size_t k0 = (size_t)(kt + 1) * 32;
            const int nb = (bi ^ 1) * 20480;
            gload16(agsrc + k0, aldst + nb);
            #pragma unroll
            for (int i = 0; i < 4; ++i) gload16(bgsrc[i] + k0, bldst[i] + nb);
            asm volatile("s_waitcnt vmcnt(5)" ::: "memory");
        } else {
            asm volatile("s_waitcnt vmcnt(0)" ::: "memory");
        }
        __builtin_amdgcn_s_barrier();
        asm volatile("" ::: "memory");

        const char* bp = lds + bi * 20480;
        bf16x8 a[4], b[4];
        #pragma unroll
        for (int m = 0; m < 4; ++m) a[m] = *(const bf16x8*)(bp + aoff[m]);
        #pragma unroll
        for (int g = 0; g < 4; ++g) b[g] = *(const bf16x8*)(bp + boff[g]);
        __builtin_amdgcn_s_setprio(1);
        #pragma unroll
        for (int m = 0; m < 4; ++m)
            #pragma unroll
            for (int g = 0; g < 4; ++g)
                acc[m][g] = __builtin_amdgcn_mfma_f32_16x16x32_bf16(a[m], b[g], acc[m][g], 0, 0, 0);
        __builtin_amdgcn_s_setprio(0);

        asm volatile("" ::: "memory");
        __builtin_amdgcn_s_barrier();
        bi ^= 1;
    }

    // ---- epilogue: fused LSTM cell ----
    const int jw = j0 + w * 16 + (l & 15);
    const float b_i = bias[jw];
    const float b_f = bias[1024 + jw];
    const float b_g = bias[2048 + jw];
    const float b_o = bias[3072 + jw];
    #pragma unroll
    for (int m = 0; m < 4; ++m) {
        #pragma unroll
        for (int r = 0; r < 4; ++r) {
            const int grow = row0 + m * 16 + ((l >> 4) << 2) + r;
            const float gi = acc[m][0][r] + b_i;
            const float gf = acc[m][1][r] + b_f;
            const float gg = acc[m][2][r] + b_g;
            const float go = acc[m][3][r] + b_o;
            const size_t ce = (size_t)grow * H_ + jw;
            const float cn = sigm(gf) * cst[ce] + sigm(gi) * tanhf(gg);
            cst[ce] = cn;
            Aout[(size_t)grow * KP_ + jw] = f2bf(sigm(go) * tanhf(cn));
        }
    }
}

// ---------------------------------------------------------------------------
// fc body: 2 batch rows per (virtual) block id. h rows + fcW chunks in LDS.
// Fuses clip, comp_vel/comp_pose writes, cumsum, bf16 feedback into A_dec.
// Needs 23296 B of LDS. 256 threads.
// ---------------------------------------------------------------------------
__device__ __forceinline__ void fc_body(
    char* lds, ushort_t* __restrict__ Ah,
    const ushort_t* __restrict__ fcWb, const float* __restrict__ fcb,
    float* __restrict__ accp, float* __restrict__ out,
    int d, int tid, int flat)
{
    ushort_t* hsb = (ushort_t*)lds;            // [2][1024] bf16 = 4 KB
    ushort_t* wc  = (ushort_t*)(lds + 4096);   // [75][128] bf16 = 18.75 KB
    const int b0 = flat * 2;
    {
        const int r = tid >> 7;
        const int k = (tid & 127) * 8;
        *(bf16x8*)(hsb + r * 1024 + k) = *(const bf16x8*)(Ah + (size_t)(b0 + r) * KP_ + k);
    }
    __syncthreads();
    const int f   = tid & 127;
    const int row = tid >> 7;
    float s = 0.f;
    for (int kc = 0; kc < 8; ++kc) {
        for (int i = tid * 8; i < 9600; i += 2048) {
            const int fi = i >> 7, ki = i & 127;
            *(bf16x8*)(wc + i) = *(const bf16x8*)(fcWb + (size_t)fi * 1024 + kc * 128 + ki);
        }
        __syncthreads();
        if (f < 75) {
            const ushort_t* hrow = hsb + row * 1024 + kc * 128;
            const ushort_t* wrow = wc + f * 128;
            #pragma unroll
            for (int k8 = 0; k8 < 128; k8 += 8) {
                const bf16x8 hv = *(const bf16x8*)(hrow + k8);
                const bf16x8 wv = *(const bf16x8*)(wrow + k8);
                #pragma unroll
                for (int u = 0; u < 8; ++u)
                    s = fmaf(bf2f((ushort_t)hv[u]), bf2f((ushort_t)wv[u]), s);
            }
        }
        __syncthreads();
    }
    if (f < 75) {
        s += fcb[f];
        s = fminf(fmaxf(s, -1.f), 1.f);
        const int b = b0 + row;
        const float p = accp[b * 75 + f] + s;
        accp[b * 75 + f] = p;
        out[OFF_CV + ((size_t)b * 49 + d) * 75 + f]     = s;
        out[OFF_CP + ((size_t)b * 50 + d + 1) * 75 + f] = p;
        Ah[(size_t)b * KP_ + 1024 + f] = f2bf(s);
    }
}

__device__ __forceinline__ void combine_body(
    const ushort_t* hpe, const ushort_t* hve,
    const float* cpe, const float* cve,
    ushort_t* Adec0, float* cde, int start, int stride)
{
    for (int idx = start; idx < B_ * H_; idx += stride) {
        const int b = idx >> 10, j = idx & 1023;
        const size_t o = (size_t)b * KP_ + j;
        Adec0[o] = f2bf(bf2f(hpe[o]) + bf2f(hve[o]));
        cde[idx] = cpe[idx] + cve[idx];
    }
}

// ---------------------------------------------------------------------------
struct MainArgs {
    ushort_t*       A[3][2];     // [pe,ve,dec][ping,pong] 1024 x KP_ bf16
    const ushort_t* W[3];        // packed 4096 x KP_ bf16 (gate-major panels)
    const float*    bias[3];     // 4096 combined bih+bhh
    float*          c[3];        // B x H fp32 cell state
    const ushort_t* pose_bf;     // [1024][50][75]
    const ushort_t* vel_bf;      // [1024][49][75]
    const ushort_t* fcWb;        // [75][1024]
    const float*    fcb;
    float*          accp;
    float*          out;
};

__device__ __forceinline__ void gsync(cg::grid_group& grid) {
    __threadfence();        // release insurance (agent-scope wb)
    grid.sync();
    __threadfence();        // acquire insurance (agent-scope inv)
}

// ---------------------------------------------------------------------------
// Persistent cooperative kernel, 512 blocks x 256 threads (2 blocks/CU).
// ---------------------------------------------------------------------------
__global__ __launch_bounds__(256, 2)
void main_kernel(MainArgs ma)
{
    cg::grid_group grid = cg::this_grid();
    __shared__ __align__(16) char lds[2 * 20480];
    const int tid  = threadIdx.x;
    const int flat = blockIdx.x;

    const int xcd  = flat & 7;
    const int slot = flat >> 3;
    const int cgd  = (xcd << 2) + (slot >> 4);   // 0..31
    const int pd   = cgd >> 4;                   // problem 0/1
    const int ctd  = cgd & 15;
    const int rtd  = slot & 15;
    int cts = 0, rts = 0;
    if (flat < 256) {
        const int s2 = flat >> 3;
        cts = ((flat & 7) << 1) + (s2 >> 4);
        rts = s2 & 15;
    }

    for (int t = 0; t < 50; ++t) {
        if (!(t == 49 && pd == 1)) {
            const ushort_t* xn = nullptr; int xstr = 0;
            if (pd == 0) { if (t < 49) { xn = ma.pose_bf + (size_t)(t + 1) * 75; xstr = 3750; } }
            else         { if (t < 48) { xn = ma.vel_bf  + (size_t)(t + 1) * 75; xstr = 3675; } }
            lstm_step_body(lds, ma.A[pd][t & 1], ma.A[pd][(t + 1) & 1],
                           ma.W[pd], ma.bias[pd], ma.c[pd], xn, xstr, ctd, rtd, tid);
        }
        gsync(grid);
    }

    combine_body(ma.A[0][0], ma.A[1][1], ma.c[0], ma.c[1],
                 ma.A[2][0], ma.c[2], flat * 256 + tid, 512 * 256);
    gsync(grid);

    for (int d = 0; d < 49; ++d) {
        if (flat < 256)
            lstm_step_body(lds, ma.A[2][d & 1], ma.A[2][(d + 1) & 1],
                           ma.W[2], ma.bias[2], ma.c[2], nullptr, 0, cts, rts, tid);
        gsync(grid);
        fc_body(lds, ma.A[2][(d + 1) & 1], ma.fcWb, ma.fcb, ma.accp, ma.out, d, tid, flat);
        gsync(grid);
    }
}

// ---------------------------------------------------------------------------
// Fallback cooperative kernel, 256 blocks x 256 threads (1 block/CU —
// co-residency essentially guaranteed). Each block runs pe then ve tile.
// ---------------------------------------------------------------------------
__global__ __launch_bounds__(256, 1)
void main_kernel_1cu(MainArgs ma)
{
    cg::grid_group grid = cg::this_grid();
    __shared__ __align__(16) char lds[2 * 20480];
    const int tid  = threadIdx.x;
    const int flat = blockIdx.x;
    const int s2 = flat >> 3;
    const int ct = ((flat & 7) << 1) + (s2 >> 4);
    const int rt = s2 & 15;

    for (int t = 0; t < 50; ++t) {
        const ushort_t* xnp = (t < 49) ? ma.pose_bf + (size_t)(t + 1) * 75 : nullptr;
        lstm_step_body(lds, ma.A[0][t & 1], ma.A[0][(t + 1) & 1],
                       ma.W[0], ma.bias[0], ma.c[0], xnp, 3750, ct, rt, tid);
        if (t < 49) {
            const ushort_t* xnv = (t < 48) ? ma.vel_bf + (size_t)(t + 1) * 75 : nullptr;
            lstm_step_body(lds, ma.A[1][t & 1], ma.A[1][(t + 1) & 1],
                           ma.W[1], ma.bias[1], ma.c[1], xnv, 3675, ct, rt, tid);
        }
        gsync(grid);
    }

    combine_body(ma.A[0][0], ma.A[1][1], ma.c[0], ma.c[1],
                 ma.A[2][0], ma.c[2], flat * 256 + tid, 256 * 256);
    gsync(grid);

    for (int d = 0; d < 49; ++d) {
        lstm_step_body(lds, ma.A[2][d & 1], ma.A[2][(d + 1) & 1],
                       ma.W[2], ma.bias[2], ma.c[2], nullptr, 0, ct, rt, tid);
        gsync(grid);
        fc_body(lds, ma.A[2][(d + 1) & 1], ma.fcWb, ma.fcb, ma.accp, ma.out, d, tid, flat);
        fc_body(lds, ma.A[2][(d + 1) & 1], ma.fcWb, ma.fcb, ma.accp, ma.out, d, tid, flat + 256);
        gsync(grid);
    }
}

// ---------------------------------------------------------------------------
// Multi-dispatch fallback kernels (round-3 path, proven).
// ---------------------------------------------------------------------------
struct StepArgs {
    const ushort_t* Ain[2];
    ushort_t*       Aout[2];
    const ushort_t* W[2];
    const float*    bias[2];
    float*          c[2];
    const ushort_t* xnext[2];
    int             xstride[2];
};

__global__ __launch_bounds__(256)
void fb_step_kernel(StepArgs sa)
{
    __shared__ __align__(16) char lds[2 * 20480];
    const int flat = blockIdx.x;
    const int xcd  = flat & 7;
    const int slot = flat >> 3;
    int p, ct;
    if (gridDim.x == 512) { const int cgx = (xcd << 2) + (slot >> 4); p = cgx >> 4; ct = cgx & 15; }
    else                  { const int cgx = (xcd << 1) + (slot >> 4); p = 0;        ct = cgx; }
    const int rt = slot & 15;
    lstm_step_body(lds, sa.Ain[p], sa.Aout[p], sa.W[p], sa.bias[p], sa.c[p],
                   sa.xnext[p], sa.xstride[p], ct, rt, threadIdx.x);
}

__global__ __launch_bounds__(256)
void fb_combine_kernel(const ushort_t* hpe, const ushort_t* hve,
                       const float* cpe, const float* cve,
                       ushort_t* Adec0, float* cde)
{
    combine_body(hpe, hve, cpe, cve, Adec0, cde,
                 blockIdx.x * 256 + threadIdx.x, gridDim.x * 256);
}

__global__ __launch_bounds__(256)
void fb_fc_kernel(ushort_t* Ah, const ushort_t* fcWb, const float* fcb,
                  float* accp, float* out, int d)
{
    __shared__ __align__(16) char lds[23296];
    fc_body(lds, Ah, fcWb, fcb, accp, out, d, threadIdx.x, blockIdx.x);
}

// ---------------------------------------------------------------------------
// Pack / prep (unchanged, proven).
// ---------------------------------------------------------------------------
__global__ __launch_bounds__(256)
void pack_kernel(const float* __restrict__ peWih, const float* __restrict__ peWhh,
                 const float* __restrict__ veWih, const float* __restrict__ veWhh,
                 const float* __restrict__ deWih, const float* __restrict__ deWhh,
                 const float* __restrict__ pe_bih, const float* __restrict__ pe_bhh,
                 const float* __restrict__ ve_bih, const float* __restrict__ ve_bhh,
                 const float* __restrict__ de_bih, const float* __restrict__ de_bhh,
                 const float* __restrict__ fcW,
                 ushort_t* __restrict__ Wp, float* __restrict__ biasp,
                 ushort_t* __restrict__ fcWb)
{
    const size_t PER = 4096UL * KP_;
    const size_t NW  = 3UL * PER;
    const size_t NB  = 3UL * 4096;
    const size_t NF  = 75UL * 1024;
    for (size_t idx = (size_t)blockIdx.x * blockDim.x + threadIdx.x;
         idx < NW + NB + NF; idx += (size_t)gridDim.x * blockDim.x) {
        if (idx < NW) {
            const int p   = (int)(idx / PER);
            const size_t rem = idx % PER;
            const int row = (int)(rem / KP_);
            const int k   = (int)(rem % KP_);
            const float* Whh = (p == 0) ? peWhh : (p == 1) ? veWhh : deWhh;
            const float* Wih = (p == 0) ? peWih : (p == 1) ? veWih : deWih;
            float v = 0.f;
            if (k < 1024)      v = Whh[(size_t)row * 1024 + k];
            else if (k < 1099) v = Wih[(size_t)row * 75 + (k - 1024)];
            Wp[idx] = f2bf(v);
        } else if (idx < NW + NB) {
            const size_t i = idx - NW;
            const int p = (int)(i / 4096);
            const int r = (int)(i % 4096);
            const float* bih = (p == 0) ? pe_bih : (p == 1) ? ve_bih : de_bih;
            const float* bhh = (p == 0) ? pe_bhh : (p == 1) ? ve_bhh : de_bhh;
            biasp[i] = bih[r] + bhh[r];
        } else {
            const size_t i = idx - NW - NB;
            fcWb[i] = f2bf(fcW[i]);
        }
    }
}

__global__ __launch_bounds__(256)
void prep_kernel(const float* __restrict__ pose, const float* __restrict__ fut,
                 const int* __restrict__ noise,
                 ushort_t* __restrict__ pose_bf, ushort_t* __restrict__ vel_bf,
                 ushort_t* __restrict__ A_pe0, ushort_t* __restrict__ A_ve0,
                 ushort_t* __restrict__ A_dec0,
                 float* __restrict__ accp, float* __restrict__ out)
{
    const size_t N0 = 1024UL * 50 * 75;
    const size_t N1 = 1024UL * 49 * 75;
    const size_t N2 = 1920000UL;
    const size_t N3 = 76800UL;
    for (size_t idx = (size_t)blockIdx.x * blockDim.x + threadIdx.x;
         idx < N0 + N1 + N2 + N3; idx += (size_t)gridDim.x * blockDim.x) {
        if (idx < N0) {
            pose_bf[idx] = f2bf(pose[idx]);
        } else if (idx < N0 + N1) {
            const size_t i = idx - N0;
            const int f = (int)(i % 75);
            const size_t rem = i / 75;
            const int t = (int)(rem % 49);
            const size_t b = rem / 49;
            float v = pose[(b * 50 + t + 1) * 75 + f] - pose[(b * 50 + t) * 75 + f];
            if (noise[(b * 50 + t + 1) * 25 + f / 3] == 1) v = 0.f;
            const ushort_t vb = f2bf(v);
            vel_bf[i] = vb;
            if (t == 0)  A_ve0[b * KP_ + 1024 + f]  = vb;
            if (t == 48) A_dec0[b * KP_ + 1024 + f] = vb;
        } else if (idx < N0 + N1 + N2) {
            const size_t i = idx - N0 - N1;
            out[i] = fut[i];
        } else {
            const size_t i = idx - N0 - N1 - N2;
            const size_t b = i / 75;
            const int f = (int)(i % 75);
            const float p0 = pose[b * 50 * 75 + f];
            A_pe0[b * KP_ + 1024 + f] = f2bf(p0);
            accp[i] = p0;
            out[OFF_CP + b * 50 * 75 + f] = p0;
        }
    }
}

extern "C" void kernel_launch(void* const* d_in, const int* in_sizes, int n_in,
                              void* d_out, int out_size, void* d_ws, size_t ws_size,
                              hipStream_t stream) {
    const float* pose   = (const float*)d_in[0];
    const float* fut    = (const float*)d_in[1];
    const int*   noise  = (const int*)  d_in[2];
    const float* peWih  = (const float*)d_in[3];
    const float* peWhh  = (const float*)d_in[4];
    const float* pe_bih = (const float*)d_in[5];
    const float* pe_bhh = (const float*)d_in[6];
    const float* veWih  = (const float*)d_in[7];
    const float* veWhh  = (const float*)d_in[8];
    const float* ve_bih = (const float*)d_in[9];
    const float* ve_bhh = (const float*)d_in[10];
    const float* deWih  = (const float*)d_in[11];
    const float* deWhh  = (const float*)d_in[12];
    const float* de_bih = (const float*)d_in[13];
    const float* de_bhh = (const float*)d_in[14];
    const float* fcW    = (const float*)d_in[15];
    const float* fcb    = (const float*)d_in[16];
    float* out = (float*)d_out;

    char* base = (char*)d_ws;
    ushort_t* Ape[2]  = {(ushort_t*)(base + 0UL * 2293760), (ushort_t*)(base + 1UL * 2293760)};
    ushort_t* Ave[2]  = {(ushort_t*)(base + 2UL * 2293760), (ushort_t*)(base + 3UL * 2293760)};
    ushort_t* Adec[2] = {(ushort_t*)(base + 4UL * 2293760), (ushort_t*)(base + 5UL * 2293760)};
    float* c_pe = (float*)(base + 13762560);
    float* c_ve = c_pe + 1048576;
    float* c_de = c_ve + 1048576;
    ushort_t* Wp    = (ushort_t*)(base + 26345472);   // 3 x 4096 x 1120
    float*    biasp = (float*)   (base + 53870592);   // 3 x 4096
    ushort_t* fcWb  = (ushort_t*)(base + 53919744);   // 75 x 1024
    ushort_t* pose_bf = (ushort_t*)(base + 54073344); // 1024x50x75
    ushort_t* vel_bf  = (ushort_t*)(base + 61753344); // 1024x49x75
    float*    accp    = (float*)   (base + 69279744); // 1024x75

    hipMemsetAsync(base, 0, 22151168, stream);

    pack_kernel<<<2048, 256, 0, stream>>>(peWih, peWhh, veWih, veWhh, deWih, deWhh,
                                          pe_bih, pe_bhh, ve_bih, ve_bhh, de_bih, de_bhh,
                                          fcW, Wp, biasp, fcWb);
    prep_kernel<<<2048, 256, 0, stream>>>(pose, fut, noise, pose_bf, vel_bf,
                                          Ape[0], Ave[0], Adec[0], accp, out);

    MainArgs ma;
    ma.A[0][0] = Ape[0];  ma.A[0][1] = Ape[1];
    ma.A[1][0] = Ave[0];  ma.A[1][1] = Ave[1];
    ma.A[2][0] = Adec[0]; ma.A[2][1] = Adec[1];
    ma.W[0] = Wp;
    ma.W[1] = Wp + 4587520;
    ma.W[2] = Wp + 9175040;
    ma.bias[0] = biasp; ma.bias[1] = biasp + 4096; ma.bias[2] = biasp + 8192;
    ma.c[0] = c_pe; ma.c[1] = c_ve; ma.c[2] = c_de;
    ma.pose_bf = pose_bf;
    ma.vel_bf  = vel_bf;
    ma.fcWb = fcWb;
    ma.fcb  = fcb;
    ma.accp = accp;
    ma.out  = out;

    void* kargs[] = {(void*)&ma};
    hipError_t e = hipLaunchCooperativeKernel((const void*)main_kernel,
                                              dim3(512), dim3(256), kargs, 0, stream);
    if (e != hipSuccess) {
        (void)hipGetLastError();   // clear sticky error
        e = hipLaunchCooperativeKernel((const void*)main_kernel_1cu,
                                       dim3(256), dim3(256), kargs, 0, stream);
    }
    if (e != hipSuccess) {
        (void)hipGetLastError();   // clear sticky error
        // ---- proven multi-dispatch fallback (round-3 path) ----
        const ushort_t* Wpe = ma.W[0];
        const ushort_t* Wve = ma.W[1];
        const ushort_t* Wde = ma.W[2];
        for (int t = 0; t < 49; ++t) {
            StepArgs sa;
            sa.Ain[0] = Ape[t & 1];  sa.Aout[0] = Ape[(t + 1) & 1];
            sa.W[0] = Wpe; sa.bias[0] = biasp; sa.c[0] = c_pe;
            sa.xnext[0] = pose_bf + (size_t)(t + 1) * 75; sa.xstride[0] = 3750;
            sa.Ain[1] = Ave[t & 1];  sa.Aout[1] = Ave[(t + 1) & 1];
            sa.W[1] = Wve; sa.bias[1] = biasp + 4096; sa.c[1] = c_ve;
            sa.xnext[1] = (t < 48) ? (vel_bf + (size_t)(t + 1) * 75) : nullptr;
            sa.xstride[1] = 3675;
            fb_step_kernel<<<512, 256, 0, stream>>>(sa);
        }
        {
            StepArgs sa;
            sa.Ain[0] = Ape[1]; sa.Aout[0] = Ape[0];
            sa.W[0] = Wpe; sa.bias[0] = biasp; sa.c[0] = c_pe;
            sa.xnext[0] = nullptr; sa.xstride[0] = 3750;
            sa.Ain[1] = sa.Ain[0]; sa.Aout[1] = sa.Aout[0];
            sa.W[1] = sa.W[0]; sa.bias[1] = sa.bias[0]; sa.c[1] = sa.c[0];
            sa.xnext[1] = nullptr; sa.xstride[1] = 3750;
            fb_step_kernel<<<256, 256, 0, stream>>>(sa);
        }
        fb_combine_kernel<<<512, 256, 0, stream>>>(Ape[0], Ave[1], c_pe, c_ve, Adec[0], c_de);
        for (int d = 0; d < 49; ++d) {
            StepArgs sa;
            sa.Ain[0] = Adec[d & 1]; sa.Aout[0] = Adec[(d + 1) & 1];
            sa.W[0] = Wde; sa.bias[0] = biasp + 8192; sa.c[0] = c_de;
            sa.xnext[0] = nullptr; sa.xstride[0] = 0;
            sa.Ain[1] = sa.Ain[0]; sa.Aout[1] = sa.Aout[0];
            sa.W[1] = sa.W[0]; sa.bias[1] = sa.bias[0]; sa.c[1] = sa.c[0];
            sa.xnext[1] = nullptr; sa.xstride[1] = 0;
            fb_step_kernel<<<256, 256, 0, stream>>>(sa);
            fb_fc_kernel<<<512, 256, 0, stream>>>(Adec[(d + 1) & 1], fcWb, fcb, accp, out, d);
        }
    }
}

// Round 6
// 4819.156 us; speedup vs baseline: 5.0217x; 5.0217x over previous
//
#include <hip/hip_runtime.h>

typedef unsigned short ushort_t;
typedef __attribute__((ext_vector_type(8))) short bf16x8;
typedef __attribute__((ext_vector_type(4))) float f32x4;

#define B_    1024
#define H_    1024
#define FEAT_ 75
#define KP_   1120          // packed K: 1024 h + 75 x + 21 zero pad
#define NK_   35            // K-steps of 32
#define LBUF  18432         // per-buffer LDS: A 2KB + B 16KB
#define OFF_CP 1920000UL    // 1024*25*75
#define OFF_CV 5760000UL    // OFF_CP + 1024*50*75

__device__ __forceinline__ float bf2f(ushort_t u) {
    unsigned x = ((unsigned)u) << 16;
    float f; __builtin_memcpy(&f, &x, 4); return f;
}
__device__ __forceinline__ ushort_t f2bf(float f) {
    unsigned x; __builtin_memcpy(&x, &f, 4);
    x += 0x7fffu + ((x >> 16) & 1u);          // RNE
    return (ushort_t)(x >> 16);
}
__device__ __forceinline__ float sigm(float x) { return 1.f / (1.f + __expf(-x)); }

__device__ __forceinline__ void gload16(const void* g, void* l) {
    __builtin_amdgcn_global_load_lds(
        (const __attribute__((address_space(1))) void*)g,
        (__attribute__((address_space(3))) void*)l, 16, 0, 0);
}

// ---------------------------------------------------------------------------
// One LSTM timestep for one (ct, rt) tile: 32 batch rows x 64 j x 4 gates,
// 4 waves, acc[2][4]. bf16 MFMA 16x16x32, D=2 pipeline, counted vmcnt(5).
// K-ROTATION: block rt starts its K-loop at kt=rot (=rt mod 35) so the 32
// row-blocks sharing this ct's weights touch DIFFERENT W K-slices at any
// instant -> W-fetch is a parallel stream, not a latency-serialized chain.
// fp32 accumulation is K-order independent.
// ---------------------------------------------------------------------------
__device__ __forceinline__ void lstm_step_body(
    char* lds,
    const ushort_t* __restrict__ Ain, ushort_t* __restrict__ Aout,
    const ushort_t* __restrict__ Wt,  const float* __restrict__ bias,
    float* __restrict__ cst,
    const ushort_t* xnext, int xstride,
    int ct, int rt, int tid)
{
    const int w    = tid >> 6;       // wave 0..3
    const int l    = tid & 63;       // lane
    const int j0   = ct * 64;
    const int row0 = rt * 32;
    const int rot  = rt >= NK_ ? rt - NK_ : rt;   // rt<=31 -> rot=rt

    // ---- x_{t+1} copy into Aout (encoders only, ct==0 blocks) ----
    if (ct == 0 && xnext) {
        for (int idx = tid; idx < 32 * 96; idx += 256) {
            const int r  = idx / 96;
            const int xi = idx - r * 96;
            const int grow = row0 + r;
            ushort_t v = (xi < FEAT_) ? xnext[(size_t)grow * xstride + xi] : (ushort_t)0;
            Aout[(size_t)grow * KP_ + 1024 + xi] = v;
        }
    }
    // pin vmcnt base: staging counts below must not include x-copy stores
    asm volatile("s_waitcnt vmcnt(0)" ::: "memory");

    // ---- staging addresses ----
    const int lc4  = l & 3;
    const int lr4  = l >> 2;                // 0..15; A uses lanes<32 (lr4 0..7)
    const int csrc = lc4 ^ (lr4 & 3);       // inverse-swizzled source chunk

    const ushort_t* agsrc = Ain + (size_t)(row0 + w * 8 + lr4) * KP_ + csrc * 8;
    char* aldst = lds + (w * 8) * 64;       // wave w stages A rows [w*8, w*8+8)

    const ushort_t* bgsrc[4];
    char* bldst[4];
    #pragma unroll
    for (int i = 0; i < 4; ++i) {
        const int wcol = w * 1024 + j0 + i * 16 + lr4;   // gate panel w
        bgsrc[i] = Wt + (size_t)wcol * KP_ + csrc * 8;
        bldst[i] = lds + 2048 + (w * 64 + i * 16) * 64;
    }

    // ---- read offsets: LDS[r][slot] holds global chunk slot^(r&3) ----
    const int chsw = (((l >> 4) ^ (l & 3)) << 4);
    int aoff[2], boff[4];
    #pragma unroll
    for (int m = 0; m < 2; ++m) aoff[m] = (m * 16 + (l & 15)) * 64 + chsw;
    #pragma unroll
    for (int g = 0; g < 4; ++g) boff[g] = 2048 + (g * 64 + w * 16 + (l & 15)) * 64 + chsw;

    f32x4 acc[2][4];
    #pragma unroll
    for (int m = 0; m < 2; ++m)
        #pragma unroll
        for (int g = 0; g < 4; ++g)
            acc[m][g] = (f32x4){0.f, 0.f, 0.f, 0.f};

    // ---- prologue: stage rotated K-step 0 ----
    {
        const size_t k0 = (size_t)rot * 32;
        if (l < 32) gload16(agsrc + k0, aldst);
        #pragma unroll
        for (int i = 0; i < 4; ++i) gload16(bgsrc[i] + k0, bldst[i]);
    }

    // ---- main loop: 2-phase, counted vmcnt, raw barriers ----
    int bi = 0;
    for (int i = 0; i < NK_; ++i) {
        if (i + 1 < NK_) {
            int kn = i + 1 + rot; if (kn >= NK_) kn -= NK_;
            const size_t k0 = (size_t)kn * 32;
            const int nb = (bi ^ 1) * LBUF;
            if (l < 32) gload16(agsrc + k0, aldst + nb);
            #pragma unroll
            for (int g = 0; g < 4; ++g) gload16(bgsrc[g] + k0, bldst[g] + nb);
            asm volatile("s_waitcnt vmcnt(5)" ::: "memory");
        } else {
            asm volatile("s_waitcnt vmcnt(0)" ::: "memory");
        }
        __builtin_amdgcn_s_barrier();
        asm volatile("" ::: "memory");

        const char* bp = lds + bi * LBUF;
        bf16x8 a[2], b[4];
        #pragma unroll
        for (int m = 0; m < 2; ++m) a[m] = *(const bf16x8*)(bp + aoff[m]);
        #pragma unroll
        for (int g = 0; g < 4; ++g) b[g] = *(const bf16x8*)(bp + boff[g]);
        __builtin_amdgcn_s_setprio(1);
        #pragma unroll
        for (int m = 0; m < 2; ++m)
            #pragma unroll
            for (int g = 0; g < 4; ++g)
                acc[m][g] = __builtin_amdgcn_mfma_f32_16x16x32_bf16(a[m], b[g], acc[m][g], 0, 0, 0);
        __builtin_amdgcn_s_setprio(0);

        asm volatile("" ::: "memory");
        __builtin_amdgcn_s_barrier();
        bi ^= 1;
    }

    // ---- epilogue: fused LSTM cell ----
    const int jw = j0 + w * 16 + (l & 15);
    const float b_i = bias[jw];
    const float b_f = bias[1024 + jw];
    const float b_g = bias[2048 + jw];
    const float b_o = bias[3072 + jw];
    #pragma unroll
    for (int m = 0; m < 2; ++m) {
        #pragma unroll
        for (int r = 0; r < 4; ++r) {
            const int grow = row0 + m * 16 + ((l >> 4) << 2) + r;
            const float gi = acc[m][0][r] + b_i;
            const float gf = acc[m][1][r] + b_f;
            const float gg = acc[m][2][r] + b_g;
            const float go = acc[m][3][r] + b_o;
            const size_t ce = (size_t)grow * H_ + jw;
            const float cn = sigm(gf) * cst[ce] + sigm(gi) * tanhf(gg);
            cst[ce] = cn;
            Aout[(size_t)grow * KP_ + jw] = f2bf(sigm(go) * tanhf(cn));
        }
    }
}

// ---------------------------------------------------------------------------
// Step kernel. Encoder (dual): grid 1024 -> per XCD 4 col-groups x 32 rt.
// Decoder / pe-only (single): grid 512 -> per XCD 2 ct x 32 rt.
// 4 blocks/CU (36KB LDS, <=128 VGPR via launch_bounds(256,4)).
// ---------------------------------------------------------------------------
struct StepArgs {
    const ushort_t* Ain[2];
    ushort_t*       Aout[2];
    const ushort_t* W[2];
    const float*    bias[2];
    float*          c[2];
    const ushort_t* xnext[2];
    int             xstride[2];
};

__global__ __launch_bounds__(256, 4)
void step_kernel(StepArgs sa)
{
    __shared__ __align__(16) char lds[2 * LBUF];
    const int flat = blockIdx.x;
    const int xcd  = flat & 7;
    const int slot = flat >> 3;
    int p, ct;
    if (gridDim.x == 1024) {      // dual problem (pe+ve encoders)
        const int cgx = (xcd << 2) + (slot >> 5);  // 0..31
        p  = cgx >> 4;
        ct = cgx & 15;
    } else {                      // single problem, grid 512
        p  = 0;
        ct = (xcd << 1) + (slot >> 5);             // 0..15
    }
    const int rt = slot & 31;
    lstm_step_body(lds, sa.Ain[p], sa.Aout[p], sa.W[p], sa.bias[p], sa.c[p],
                   sa.xnext[p], sa.xstride[p], ct, rt, threadIdx.x);
}

// ---------------------------------------------------------------------------
// Pack: 3 weight sets -> bf16 [4096][1120] (Whh | Wih | 0pad), combined
// biases, fc_W -> bf16.
// ---------------------------------------------------------------------------
__global__ __launch_bounds__(256)
void pack_kernel(const float* __restrict__ peWih, const float* __restrict__ peWhh,
                 const float* __restrict__ veWih, const float* __restrict__ veWhh,
                 const float* __restrict__ deWih, const float* __restrict__ deWhh,
                 const float* __restrict__ pe_bih, const float* __restrict__ pe_bhh,
                 const float* __restrict__ ve_bih, const float* __restrict__ ve_bhh,
                 const float* __restrict__ de_bih, const float* __restrict__ de_bhh,
                 const float* __restrict__ fcW,
                 ushort_t* __restrict__ Wp, float* __restrict__ biasp,
                 ushort_t* __restrict__ fcWb)
{
    const size_t PER = 4096UL * KP_;
    const size_t NW  = 3UL * PER;
    const size_t NB  = 3UL * 4096;
    const size_t NF  = 75UL * 1024;
    for (size_t idx = (size_t)blockIdx.x * blockDim.x + threadIdx.x;
         idx < NW + NB + NF; idx += (size_t)gridDim.x * blockDim.x) {
        if (idx < NW) {
            const int p   = (int)(idx / PER);
            const size_t rem = idx % PER;
            const int row = (int)(rem / KP_);
            const int k   = (int)(rem % KP_);
            const float* Whh = (p == 0) ? peWhh : (p == 1) ? veWhh : deWhh;
            const float* Wih = (p == 0) ? peWih : (p == 1) ? veWih : deWih;
            float v = 0.f;
            if (k < 1024)      v = Whh[(size_t)row * 1024 + k];
            else if (k < 1099) v = Wih[(size_t)row * 75 + (k - 1024)];
            Wp[idx] = f2bf(v);
        } else if (idx < NW + NB) {
            const size_t i = idx - NW;
            const int p = (int)(i / 4096);
            const int r = (int)(i % 4096);
            const float* bih = (p == 0) ? pe_bih : (p == 1) ? ve_bih : de_bih;
            const float* bhh = (p == 0) ? pe_bhh : (p == 1) ? ve_bhh : de_bhh;
            biasp[i] = bih[r] + bhh[r];
        } else {
            const size_t i = idx - NW - NB;
            fcWb[i] = f2bf(fcW[i]);
        }
    }
}

// ---------------------------------------------------------------------------
// Prep: pose->bf16, vel (noise-masked)->bf16, x inits for A_pe0/A_ve0/A_dec0,
// future passthrough, comp_pose[:,0], acc_pose init.
// ---------------------------------------------------------------------------
__global__ __launch_bounds__(256)
void prep_kernel(const float* __restrict__ pose, const float* __restrict__ fut,
                 const int* __restrict__ noise,
                 ushort_t* __restrict__ pose_bf, ushort_t* __restrict__ vel_bf,
                 ushort_t* __restrict__ A_pe0, ushort_t* __restrict__ A_ve0,
                 ushort_t* __restrict__ A_dec0,
                 float* __restrict__ accp, float* __restrict__ out)
{
    const size_t N0 = 1024UL * 50 * 75;
    const size_t N1 = 1024UL * 49 * 75;
    const size_t N2 = 1920000UL;
    const size_t N3 = 76800UL;
    for (size_t idx = (size_t)blockIdx.x * blockDim.x + threadIdx.x;
         idx < N0 + N1 + N2 + N3; idx += (size_t)gridDim.x * blockDim.x) {
        if (idx < N0) {
            pose_bf[idx] = f2bf(pose[idx]);
        } else if (idx < N0 + N1) {
            const size_t i = idx - N0;
            const int f = (int)(i % 75);
            const size_t rem = i / 75;
            const int t = (int)(rem % 49);
            const size_t b = rem / 49;
            float v = pose[(b * 50 + t + 1) * 75 + f] - pose[(b * 50 + t) * 75 + f];
            if (noise[(b * 50 + t + 1) * 25 + f / 3] == 1) v = 0.f;
            const ushort_t vb = f2bf(v);
            vel_bf[i] = vb;
            if (t == 0)  A_ve0[b * KP_ + 1024 + f]  = vb;
            if (t == 48) A_dec0[b * KP_ + 1024 + f] = vb;
        } else if (idx < N0 + N1 + N2) {
            const size_t i = idx - N0 - N1;
            out[i] = fut[i];
        } else {
            const size_t i = idx - N0 - N1 - N2;
            const size_t b = i / 75;
            const int f = (int)(i % 75);
            const float p0 = pose[b * 50 * 75 + f];
            A_pe0[b * KP_ + 1024 + f] = f2bf(p0);
            accp[i] = p0;
            out[OFF_CP + b * 50 * 75 + f] = p0;
        }
    }
}

// h_dec0 = bf16(h_pe + h_ve) into A_dec0; c_de = c_pe + c_ve
__global__ __launch_bounds__(256)
void combine_kernel(const ushort_t* __restrict__ hpe, const ushort_t* __restrict__ hve,
                    const float* __restrict__ cpe, const float* __restrict__ cve,
                    ushort_t* __restrict__ Adec0, float* __restrict__ cde)
{
    const int idx = blockIdx.x * blockDim.x + threadIdx.x;
    if (idx >= B_ * H_) return;
    const int b = idx >> 10, j = idx & 1023;
    const size_t o = (size_t)b * KP_ + j;
    Adec0[o] = f2bf(bf2f(hpe[o]) + bf2f(hve[o]));
    cde[idx] = cpe[idx] + cve[idx];
}

// ---------------------------------------------------------------------------
// Decoder fc: s = clip(h @ fcW^T + b), fused comp_vel/comp_pose writes,
// cumsum, bf16 feedback into A_dec x-region. 4-way ILP dot. (round-3 proven)
// ---------------------------------------------------------------------------
__global__ __launch_bounds__(128)
void fc_kernel(const ushort_t* __restrict__ Adec,
               ushort_t* __restrict__ Adec_w,
               const ushort_t* __restrict__ fcWb, const float* __restrict__ fcb,
               float* __restrict__ accp, float* __restrict__ out, int t)
{
    __shared__ float hs[1024];
    const int b = blockIdx.x;
    const ushort_t* hrow = Adec + (size_t)b * KP_;
    {
        const int k = threadIdx.x * 8;
        const bf16x8 v = *(const bf16x8*)(hrow + k);
        #pragma unroll
        for (int u = 0; u < 8; ++u) hs[k + u] = bf2f((ushort_t)v[u]);
    }
    __syncthreads();
    const int f = threadIdx.x;
    if (f < FEAT_) {
        const ushort_t* wr = fcWb + (size_t)f * 1024;
        float s0 = fcb[f], s1 = 0.f, s2 = 0.f, s3 = 0.f;
        for (int k = 0; k < 1024; k += 32) {
            const bf16x8 w0 = *(const bf16x8*)(wr + k);
            const bf16x8 w1 = *(const bf16x8*)(wr + k + 8);
            const bf16x8 w2 = *(const bf16x8*)(wr + k + 16);
            const bf16x8 w3 = *(const bf16x8*)(wr + k + 24);
            #pragma unroll
            for (int u = 0; u < 8; ++u) {
                s0 = fmaf(hs[k + u],      bf2f((ushort_t)w0[u]), s0);
                s1 = fmaf(hs[k + 8 + u],  bf2f((ushort_t)w1[u]), s1);
                s2 = fmaf(hs[k + 16 + u], bf2f((ushort_t)w2[u]), s2);
                s3 = fmaf(hs[k + 24 + u], bf2f((ushort_t)w3[u]), s3);
            }
        }
        float s = (s0 + s1) + (s2 + s3);
        s = fminf(fmaxf(s, -1.f), 1.f);
        const float p = accp[b * FEAT_ + f] + s;
        accp[b * FEAT_ + f] = p;
        out[OFF_CV + ((size_t)b * 49 + t) * FEAT_ + f]     = s;
        out[OFF_CP + ((size_t)b * 50 + t + 1) * FEAT_ + f] = p;
        Adec_w[(size_t)b * KP_ + 1024 + f] = f2bf(s);
    }
}

extern "C" void kernel_launch(void* const* d_in, const int* in_sizes, int n_in,
                              void* d_out, int out_size, void* d_ws, size_t ws_size,
                              hipStream_t stream) {
    const float* pose   = (const float*)d_in[0];
    const float* fut    = (const float*)d_in[1];
    const int*   noise  = (const int*)  d_in[2];
    const float* peWih  = (const float*)d_in[3];
    const float* peWhh  = (const float*)d_in[4];
    const float* pe_bih = (const float*)d_in[5];
    const float* pe_bhh = (const float*)d_in[6];
    const float* veWih  = (const float*)d_in[7];
    const float* veWhh  = (const float*)d_in[8];
    const float* ve_bih = (const float*)d_in[9];
    const float* ve_bhh = (const float*)d_in[10];
    const float* deWih  = (const float*)d_in[11];
    const float* deWhh  = (const float*)d_in[12];
    const float* de_bih = (const float*)d_in[13];
    const float* de_bhh = (const float*)d_in[14];
    const float* fcW    = (const float*)d_in[15];
    const float* fcb    = (const float*)d_in[16];
    float* out = (float*)d_out;

    char* base = (char*)d_ws;
    ushort_t* Ape[2]  = {(ushort_t*)(base + 0UL * 2293760), (ushort_t*)(base + 1UL * 2293760)};
    ushort_t* Ave[2]  = {(ushort_t*)(base + 2UL * 2293760), (ushort_t*)(base + 3UL * 2293760)};
    ushort_t* Adec[2] = {(ushort_t*)(base + 4UL * 2293760), (ushort_t*)(base + 5UL * 2293760)};
    float* c_pe = (float*)(base + 13762560);
    float* c_ve = c_pe + 1048576;
    float* c_de = c_ve + 1048576;
    ushort_t* Wp    = (ushort_t*)(base + 26345472);   // 3 x 4096 x 1120
    float*    biasp = (float*)   (base + 53870592);   // 3 x 4096
    ushort_t* fcWb  = (ushort_t*)(base + 53919744);   // 75 x 1024
    ushort_t* pose_bf = (ushort_t*)(base + 54073344); // 1024x50x75
    ushort_t* vel_bf  = (ushort_t*)(base + 61753344); // 1024x49x75
    float*    accp    = (float*)   (base + 69279744); // 1024x75

    hipMemsetAsync(base, 0, 22151168, stream);

    pack_kernel<<<2048, 256, 0, stream>>>(peWih, peWhh, veWih, veWhh, deWih, deWhh,
                                          pe_bih, pe_bhh, ve_bih, ve_bhh, de_bih, de_bhh,
                                          fcW, Wp, biasp, fcWb);
    prep_kernel<<<2048, 256, 0, stream>>>(pose, fut, noise, pose_bf, vel_bf,
                                          Ape[0], Ave[0], Adec[0], accp, out);

    const ushort_t* Wpe = Wp;
    const ushort_t* Wve = Wp + 4587520;
    const ushort_t* Wde = Wp + 9175040;

    // --- encoders: dual launch (pe + ve) for t<49, single pe at t=49 ---
    for (int t = 0; t < 49; ++t) {
        StepArgs sa;
        sa.Ain[0] = Ape[t & 1];  sa.Aout[0] = Ape[(t + 1) & 1];
        sa.W[0] = Wpe; sa.bias[0] = biasp; sa.c[0] = c_pe;
        sa.xnext[0] = pose_bf + (size_t)(t + 1) * 75; sa.xstride[0] = 3750;
        sa.Ain[1] = Ave[t & 1];  sa.Aout[1] = Ave[(t + 1) & 1];
        sa.W[1] = Wve; sa.bias[1] = biasp + 4096; sa.c[1] = c_ve;
        sa.xnext[1] = (t < 48) ? (vel_bf + (size_t)(t + 1) * 75) : nullptr;
        sa.xstride[1] = 3675;
        step_kernel<<<1024, 256, 0, stream>>>(sa);
    }
    {
        StepArgs sa;
        sa.Ain[0] = Ape[1]; sa.Aout[0] = Ape[0];
        sa.W[0] = Wpe; sa.bias[0] = biasp; sa.c[0] = c_pe;
        sa.xnext[0] = nullptr; sa.xstride[0] = 3750;
        sa.Ain[1] = sa.Ain[0]; sa.Aout[1] = sa.Aout[0];
        sa.W[1] = sa.W[0]; sa.bias[1] = sa.bias[0]; sa.c[1] = sa.c[0];
        sa.xnext[1] = nullptr; sa.xstride[1] = 3750;
        step_kernel<<<512, 256, 0, stream>>>(sa);
    }

    combine_kernel<<<4096, 256, 0, stream>>>(Ape[0], Ave[1], c_pe, c_ve, Adec[0], c_de);

    // --- decoder: 49 steps, fc feeds back into the next A_dec buffer ---
    for (int d = 0; d < 49; ++d) {
        StepArgs sa;
        sa.Ain[0] = Adec[d & 1]; sa.Aout[0] = Adec[(d + 1) & 1];
        sa.W[0] = Wde; sa.bias[0] = biasp + 8192; sa.c[0] = c_de;
        sa.xnext[0] = nullptr; sa.xstride[0] = 0;
        sa.Ain[1] = sa.Ain[0]; sa.Aout[1] = sa.Aout[0];
        sa.W[1] = sa.W[0]; sa.bias[1] = sa.bias[0]; sa.c[1] = sa.c[0];
        sa.xnext[1] = nullptr; sa.xstride[1] = 0;
        step_kernel<<<512, 256, 0, stream>>>(sa);
        fc_kernel<<<B_, 128, 0, stream>>>(Adec[(d + 1) & 1], Adec[(d + 1) & 1],
                                          fcWb, fcb, accp, out, d);
    }
}